// Round 3
// baseline (380.220 us; speedup 1.0000x reference)
//
#include <hip/hip_runtime.h>
#include <math.h>

#define NN 8192        // n_nodes
#define NE 262144      // edges per adjacency list
#define TOTAL (2*NE)   // 524288 edges total; 2048 blocks @ 256
#define CSTR 16        // rowsum stride in floats: one counter per 64B line
#define CNT_BYTES ((size_t)NN * CSTR * 4)   // 512 KB

typedef float f4 __attribute__((ext_vector_type(4)));

// out has 8192*8192 = 64M floats = 16M f4. 524288 threads -> 32 f4/thread.
#define NF4 (NN * (size_t)NN / 4)           // 16777216

// K1: fused output zero-fill + blended row-sum accumulation.
//   - Each thread handles ONE edge: non-returning atomicAdd(rowsum[r], w*v).
//     Non-returning -> fire-and-forget, no latency chain; 8192 padded words.
//   - Each thread streams 32 nontemporal f4 zeros into out (fully coalesced,
//     k*TOTAL+i pattern). The 256MB fill (~43us at fill rate) hides all
//     atomic latency.
__global__ __launch_bounds__(256) void zero_rowsum_kernel(
        const int* __restrict__ rows_s, const float* __restrict__ vals_s,
        const int* __restrict__ rows_t, const float* __restrict__ vals_t,
        const float* __restrict__ gamma,
        float* __restrict__ rowsum, float* __restrict__ out) {
    int i = blockIdx.x * blockDim.x + threadIdx.x;
    float alpha = 1.0f / (1.0f + expf(-gamma[0]));
    int r; float wv;
    if (i < NE) { r = rows_s[i]; wv = alpha * vals_s[i]; }               // block-uniform branch
    else { int j = i - NE; r = rows_t[j]; wv = (1.0f - alpha) * vals_t[j]; }
    atomicAdd(&rowsum[r * CSTR], wv);   // non-returning (result unused)

    f4* out4 = (f4*)out;
    f4 z = {0.f, 0.f, 0.f, 0.f};
    #pragma unroll
    for (int k = 0; k < 32; ++k) {
        __builtin_nontemporal_store(z, &out4[(size_t)k * TOTAL + i]);
    }
}

// K2: normalized sparse scatter. One edge per thread:
//   out[r][c] += (w*v) / rowsum[r]   via non-returning float atomicAdd.
// Atomics (not stores) because duplicate (r,c) pairs must SUM (~2k expected
// among 524288 edges into 67M cells). rowsum reads hit 512KB of L2, broadcast.
__global__ __launch_bounds__(256) void scatter_kernel(
        const int* __restrict__ rows_s, const int* __restrict__ cols_s,
        const float* __restrict__ vals_s,
        const int* __restrict__ rows_t, const int* __restrict__ cols_t,
        const float* __restrict__ vals_t,
        const float* __restrict__ gamma,
        const float* __restrict__ rowsum,
        float* __restrict__ out) {
    int i = blockIdx.x * blockDim.x + threadIdx.x;
    float alpha = 1.0f / (1.0f + expf(-gamma[0]));
    int r, c; float wv;
    if (i < NE) { r = rows_s[i]; c = cols_s[i]; wv = alpha * vals_s[i]; }
    else { int j = i - NE; r = rows_t[j]; c = cols_t[j]; wv = (1.0f - alpha) * vals_t[j]; }
    float s = rowsum[r * CSTR];
    // Reference: rows with zero sum divide by 1. (Rows with no edges never
    // reach here; this guards the measure-zero all-zero-vals row.)
    float q = wv / (s == 0.0f ? 1.0f : s);
    atomicAdd(&out[(size_t)r * NN + c], q);
}

extern "C" void kernel_launch(void* const* d_in, const int* in_sizes, int n_in,
                              void* d_out, int out_size, void* d_ws, size_t ws_size,
                              hipStream_t stream) {
    const int*   rows_s = (const int*)  d_in[0];
    const int*   cols_s = (const int*)  d_in[1];
    const float* vals_s = (const float*)d_in[2];
    const int*   rows_t = (const int*)  d_in[3];
    const int*   cols_t = (const int*)  d_in[4];
    const float* vals_t = (const float*)d_in[5];
    const float* gamma  = (const float*)d_in[6];

    float* out    = (float*)d_out;
    float* rowsum = (float*)d_ws;       // [NN*CSTR], padded, only [r*16] used

    // Zero the padded row-sum counters (ws is poisoned with 0xAA).
    (void)hipMemsetAsync(d_ws, 0, CNT_BYTES, stream);

    zero_rowsum_kernel<<<TOTAL / 256, 256, 0, stream>>>(
        rows_s, vals_s, rows_t, vals_t, gamma, rowsum, out);
    scatter_kernel<<<TOTAL / 256, 256, 0, stream>>>(
        rows_s, cols_s, vals_s, rows_t, cols_t, vals_t, gamma, rowsum, out);
}

// Round 5
// 364.437 us; speedup vs baseline: 1.0433x; 1.0433x over previous
//
#include <hip/hip_runtime.h>
#include <math.h>

#define NN 8192        // n_nodes
#define NE 262144      // edges per adjacency list
#define TOTAL (2*NE)   // 524288 threads; 2048 blocks @ 256

typedef float f4 __attribute__((ext_vector_type(4)));

// K1: fused 256MB zero-sweep + blended row-sum accumulation.
//   Store pattern: wave w owns the contiguous 32KB span [w*2048, (w+1)*2048)
//   in f4 units; each of its 32 store instructions writes a lane-coalesced
//   1KB chunk, and consecutive instructions sweep adjacent chunks
//   (fillBuffer-style HBM locality; R3's k*TOTAL+i pattern scattered 1KB
//   fragments at 8MB strides and measured ~57% of fill rate).
//   Program order: stores FIRST (addresses depend only on threadIdx), edge
//   load + non-returning rowsum atomic LAST, so the edge-load waitcnt never
//   blocks store issue.
__global__ __launch_bounds__(256) void zero_rowsum_kernel(
        const int* __restrict__ rows_s, const float* __restrict__ vals_s,
        const int* __restrict__ rows_t, const float* __restrict__ vals_t,
        const float* __restrict__ gamma,
        float* __restrict__ rowsum, float* __restrict__ out) {
    int i = blockIdx.x * blockDim.x + threadIdx.x;

    int wave = i >> 6;                 // 0..8191
    int lane = i & 63;
    f4* out4 = (f4*)out;
    f4 z = {0.f, 0.f, 0.f, 0.f};
    size_t base = (size_t)wave * 2048 + lane;   // 2048 f4 = 32KB per wave
    #pragma unroll
    for (int k = 0; k < 32; ++k) {
        __builtin_nontemporal_store(z, &out4[base + (size_t)(k * 64)]);
    }

    // Edge work after the stores are issued.
    float alpha = 1.0f / (1.0f + expf(-gamma[0]));
    int r; float wv;
    if (i < NE) { r = rows_s[i]; wv = alpha * vals_s[i]; }               // block-uniform branch
    else { int j = i - NE; r = rows_t[j]; wv = (1.0f - alpha) * vals_t[j]; }
    atomicAdd(&rowsum[r], wv);         // non-returning: fire-and-forget
}

// K2: normalized sparse scatter. One edge per thread:
//   out[r][c] += (w*v) / rowsum[r]   via non-returning float atomicAdd.
// Atomics (not stores) because duplicate (r,c) pairs must SUM. rowsum is
// 32KB, L2-resident from K1. ~524288 scattered 64B-line RMWs ≈ 66MB of HBM
// traffic ≈ 15-20us.
__global__ __launch_bounds__(256) void scatter_kernel(
        const int* __restrict__ rows_s, const int* __restrict__ cols_s,
        const float* __restrict__ vals_s,
        const int* __restrict__ rows_t, const int* __restrict__ cols_t,
        const float* __restrict__ vals_t,
        const float* __restrict__ gamma,
        const float* __restrict__ rowsum,
        float* __restrict__ out) {
    int i = blockIdx.x * blockDim.x + threadIdx.x;
    float alpha = 1.0f / (1.0f + expf(-gamma[0]));
    int r, c; float wv;
    if (i < NE) { r = rows_s[i]; c = cols_s[i]; wv = alpha * vals_s[i]; }
    else { int j = i - NE; r = rows_t[j]; c = cols_t[j]; wv = (1.0f - alpha) * vals_t[j]; }
    float s = rowsum[r];
    // Rows with no edges never reach here; guard the measure-zero all-zero
    // row to match the reference's divide-by-1.
    float q = wv / (s == 0.0f ? 1.0f : s);
    atomicAdd(&out[(size_t)r * NN + c], q);
}

extern "C" void kernel_launch(void* const* d_in, const int* in_sizes, int n_in,
                              void* d_out, int out_size, void* d_ws, size_t ws_size,
                              hipStream_t stream) {
    const int*   rows_s = (const int*)  d_in[0];
    const int*   cols_s = (const int*)  d_in[1];
    const float* vals_s = (const float*)d_in[2];
    const int*   rows_t = (const int*)  d_in[3];
    const int*   cols_t = (const int*)  d_in[4];
    const float* vals_t = (const float*)d_in[5];
    const float* gamma  = (const float*)d_in[6];

    float* out    = (float*)d_out;
    float* rowsum = (float*)d_ws;       // [NN] floats, 32KB, unpadded

    // Zero the row-sum accumulators (ws is poisoned with 0xAA).
    (void)hipMemsetAsync(d_ws, 0, (size_t)NN * 4, stream);

    zero_rowsum_kernel<<<TOTAL / 256, 256, 0, stream>>>(
        rows_s, vals_s, rows_t, vals_t, gamma, rowsum, out);
    scatter_kernel<<<TOTAL / 256, 256, 0, stream>>>(
        rows_s, cols_s, vals_s, rows_t, cols_t, vals_t, gamma, rowsum, out);
}